// Round 8
// baseline (44.593 us; speedup 1.0000x reference)
//
#include <hip/hip_runtime.h>

// TT-core contraction: C[a,c,i,k,b,d] = sum_j A[a,i,j,b] * B[c,j,k,d]
// A: [RA0, M, N, RA1=64], B: [RB0, N, P, RB1=16]
// C flat f32x4 index: (((a*RB0+c)*M+i)*P + k)*256 + tid   (tid = b*4+d4)
//
// Round 8 delta vs round 7: NO LDS, NO BARRIER. B values are read directly
// from global (L1-resident broadcast: per wave per j one 64B segment shared
// 16-ways); each wave runs fully independently, stores start immediately
// after its A-loads. NTT doubled (core2 4->8) to amortize block prologues
// (2562 blocks, 160KB of contiguous stores per core2 block). Plain stores
// (round-7 proven: cached writeback > nt by 20%).

typedef float f32x4 __attribute__((ext_vector_type(4)));

// f32x4 bases of each core's output region:
#define O0 0
#define O1 2048
#define O2 4196352
#define O3 14682112
#define O4 15730688

// block ranges: core2 first (dominant)
#define B2 1024            // 8192 t / NTT=8
#define B1 1024            // 8192 t / 8
#define B3 512             // 4096 t / 8
#define NBLK (B2 + B1 + B3 + 2)   // + core0, core4 = 2562

template<int M, int N, int P, int RB0, int NTT>
__device__ __forceinline__ void core_block(
    const float* __restrict__ A, const float* __restrict__ Bg,
    f32x4* __restrict__ out4, int bl, int tid)
{
    constexpr int SLAB = N * P * 4;               // f32x4 per B c-slab
    constexpr int NTC  = (NTT < M) ? NTT : M;     // t's sharing one c
    constexpr int NG   = NTT / NTC;               // distinct c groups
    const int t0 = bl * NTT;
    const int b  = tid >> 2;
    const int d4 = tid & 3;

    // --- A into registers (one-time; 64B-granule, L1/L2-served) ---
    float areg[NTT][N];
#pragma unroll
    for (int t = 0; t < NTT; ++t) {
        const int tt = t0 + t;
        const int i  = tt & (M - 1);
        const int a  = tt / (M * RB0);
        const float* Ap = A + ((a * M + i) * N) * 64 + b;
#pragma unroll
        for (int j = 0; j < N; ++j) areg[t][j] = Ap[j * 64];
    }

    // --- compute + streaming stores; B read per (group,k) straight from
    //     global (L1 broadcast), reused across all NTC t's ---
    const f32x4* Bg4 = reinterpret_cast<const f32x4*>(Bg);
#pragma unroll
    for (int g = 0; g < NG; ++g) {
        const int c = ((t0 + g * NTC) / M) & (RB0 - 1);
        const f32x4* Bc = Bg4 + c * SLAB + d4;
#pragma unroll
        for (int k = 0; k < P; ++k) {
            f32x4 Bk[N];
#pragma unroll
            for (int j = 0; j < N; ++j)
                Bk[j] = Bc[(j * P + k) * 4];
#pragma unroll
            for (int tl = 0; tl < NTC; ++tl) {
                const int t = g * NTC + tl;
                f32x4 acc = (f32x4)(0.f);
#pragma unroll
                for (int j = 0; j < N; ++j)
                    acc += areg[t][j] * Bk[j];
                out4[((t0 + t) * P + k) * 256 + tid] = acc;
            }
        }
    }
}

// core4: x4 [64,2,8,1] * w4 [16,8,1,1] -> out [1024,2,1,1]; o=(a*16+c)*2+i
__device__ __forceinline__ f32x4 core4_val(const float* __restrict__ x4,
                                           const float* __restrict__ w4,
                                           int w) {
    const int a  = w >> 3;
    const int c0 = (2 * w) & 15;
    const float* xr0 = x4 + (a * 2 + 0) * 8;
    const float* xr1 = x4 + (a * 2 + 1) * 8;
    const float* wc0 = w4 + c0 * 8;
    const float* wc1 = w4 + (c0 + 1) * 8;
    f32x4 acc = (f32x4)(0.f);
#pragma unroll
    for (int j = 0; j < 8; ++j) {
        acc.x = fmaf(xr0[j], wc0[j], acc.x);
        acc.y = fmaf(xr1[j], wc0[j], acc.y);
        acc.z = fmaf(xr0[j], wc1[j], acc.z);
        acc.w = fmaf(xr1[j], wc1[j], acc.w);
    }
    return acc;
}

__global__ __launch_bounds__(256) void fused_tt_kernel(
    const float* __restrict__ x0, const float* __restrict__ x1,
    const float* __restrict__ x2, const float* __restrict__ x3,
    const float* __restrict__ x4,
    const float* __restrict__ w0, const float* __restrict__ w1,
    const float* __restrict__ w2, const float* __restrict__ w3,
    const float* __restrict__ w4,
    float* __restrict__ out)
{
    const int blk = blockIdx.x;
    const int tid = threadIdx.x;
    f32x4* o4 = reinterpret_cast<f32x4*>(out);

    if (blk < B2) {
        core_block<8, 8, 5, 16, 8>(x2, w2, o4 + O2, blk, tid);
    } else if (blk < B2 + B1) {
        core_block<8, 4, 2, 16, 8>(x1, w1, o4 + O1, blk - B2, tid);
    } else if (blk < B2 + B1 + B3) {
        core_block<4, 4, 1, 16, 8>(x3, w3, o4 + O3, blk - B2 - B1, tid);
    } else if (blk == B2 + B1 + B3) {
        core_block<8, 3, 1, 1, 8>(x0, w0, o4 + O0, 0, tid);
    } else {
        // core4: 512 f32x4, one block, 2 iters
#pragma unroll
        for (int it = 0; it < 2; ++it) {
            const int w = it * 256 + tid;
            o4[O4 + w] = core4_val(x4, w4, w);
        }
    }
}

extern "C" void kernel_launch(void* const* d_in, const int* in_sizes, int n_in,
                              void* d_out, int out_size, void* d_ws, size_t ws_size,
                              hipStream_t stream) {
    const float* x0 = (const float*)d_in[0];
    const float* x1 = (const float*)d_in[1];
    const float* x2 = (const float*)d_in[2];
    const float* x3 = (const float*)d_in[3];
    const float* x4 = (const float*)d_in[4];
    const float* w0 = (const float*)d_in[5];
    const float* w1 = (const float*)d_in[6];
    const float* w2 = (const float*)d_in[7];
    const float* w3 = (const float*)d_in[8];
    const float* w4 = (const float*)d_in[9];
    float* out = (float*)d_out;

    fused_tt_kernel<<<NBLK, 256, 0, stream>>>(
        x0, x1, x2, x3, x4, w0, w1, w2, w3, w4, out);
}